// Round 5
// baseline (223.218 us; speedup 1.0000x reference)
//
#include <hip/hip_runtime.h>
#include <hip/hip_bf16.h>

// B=8, L=128, R=2048, E=32, F=64
#define NB 8
#define NL 128
#define NR 2048
#define NE 32
#define NF 64
#define RT 128                // r-rows per block
#define NRT (NR / RT)         // 16 r-tiles
#define EH 4                  // e-groups (blocks) per (b, rt)
#define EPB (NE / EH)         // 8 e's per block
#define NTHREADS 256
#define NWAVES (NTHREADS / 64)

typedef __attribute__((ext_vector_type(4)))  float f32x4;
typedef __attribute__((ext_vector_type(16))) float f32x16;
typedef __attribute__((ext_vector_type(8)))  short s16x8;
typedef __attribute__((ext_vector_type(2)))  unsigned int u32x2;

// (bf16(b) << 16) | bf16(a), round-half-up: +0x8000 then v_perm byte-select
__device__ __forceinline__ unsigned bf16pair(float a, float b) {
    union { float f; unsigned u; } ua, ub; ua.f = a; ub.f = b;
    return __builtin_amdgcn_perm(ub.u + 0x8000u, ua.u + 0x8000u, 0x07060302u);
}

__device__ __forceinline__ u32x2 pack4(f32x4 v) {
    u32x2 r;
    r.x = bf16pair(v.x, v.y);
    r.y = bf16pair(v.z, v.w);
    return r;
}

// 2 blocks/CU (64KB LDS), 2 waves/SIMD (VGPR <= 256)
__global__ __launch_bounds__(NTHREADS, 2) void ff_kernel(
    const float* __restrict__ lig_feat,
    const float* __restrict__ rec_feat,
    const float* __restrict__ lig_coord,
    const float* __restrict__ rec_coord,
    float* __restrict__ out)
{
    // bf16 tiles; rows of 64 elems = 8 x 16B chunks, chunk XOR-swizzled by (row&7)
    __shared__ __align__(16) unsigned short sA[2][NL * NF];  // 2 x 16 KB
    __shared__ __align__(16) unsigned short sB[2][RT * NF];  // 2 x 16 KB
    __shared__ float sLc[3][NL];
    __shared__ float sRc[3][RT];
    __shared__ float sRed[NWAVES];

    const int blk = blockIdx.x;
    const int eh  = blk & (EH - 1);
    const int rt  = (blk >> 2) & (NRT - 1);
    const int b   = blk >> 6;            // 8*16*4 = 512 blocks
    const int e0  = eh * EPB;
    const int r0  = rt * RT;
    const int t   = threadIdx.x;
    const int lane = t & 63;
    const int wv   = t >> 6;

    // ---- coords to LDS, issue e0 loads ----
    for (int i = t; i < 3 * NL; i += NTHREADS) {
        const int c = i >> 7, l = i & 127;
        sLc[c][l] = lig_coord[((long)b * NL + l) * 3 + c];
    }
    for (int i = t; i < 3 * RT; i += NTHREADS) {
        const int c = i >> 7, r = i & 127;
        sRc[c][r] = rec_coord[((long)b * NR + r0 + r) * 3 + c];
    }

    f32x4 tA[8], tB[8];
    #pragma unroll
    for (int j = 0; j < 8; ++j) {                // lig: 2048 float4
        const int idx = t + NTHREADS * j;
        const int f4 = idx & 15, l = idx >> 4;
        tA[j] = *(const f32x4*)(lig_feat + (((long)b * NL + l) * NE + e0) * NF + f4 * 4);
    }
    #pragma unroll
    for (int j = 0; j < 8; ++j) {                // rec: 2048 float4
        const int idx = t + NTHREADS * j;
        const int f4 = idx & 15, r = idx >> 4;
        tB[j] = *(const f32x4*)(rec_feat + (((long)b * NR + r0 + r) * NE + e0) * NF + f4 * 4);
    }
    __syncthreads();   // coords visible

    // ---- per-wave 64x64 macro-tile (2x2 of 32x32); distances once, in regs ----
    const int n  = lane & 31;
    const int h  = lane >> 5;
    const int wl = wv >> 1;              // 0..1 over L/64
    const int wr = wv & 1;               // 0..1 over RT/64
    float d[2][2][16];
    #pragma unroll
    for (int j2 = 0; j2 < 2; ++j2) {
        const int col = wr * 64 + j2 * 32 + n;
        const float rx = sRc[0][col], ry = sRc[1][col], rz = sRc[2][col];
        #pragma unroll
        for (int i2 = 0; i2 < 2; ++i2) {
            #pragma unroll
            for (int i = 0; i < 16; ++i) {
                const int row = wl * 64 + i2 * 32 + 4 * h + (i & 3) + ((i >> 2) << 3);
                const float dx = sLc[0][row] - rx;
                const float dy = sLc[1][row] - ry;
                const float dz = sLc[2][row] - rz;
                d[i2][j2][i] = sqrtf(dx * dx + dy * dy + dz * dz);
            }
        }
    }

    // ---- write e0 into buf0, prefetch e1 into regs ----
    #pragma unroll
    for (int j = 0; j < 8; ++j) {
        const int idx = t + NTHREADS * j;
        const int f4 = idx & 15, l = idx >> 4;
        const int pos = (((f4 >> 1) ^ (l & 7)) << 3) + ((f4 & 1) << 2);
        *(u32x2*)&sA[0][l * NF + pos] = pack4(tA[j]);
    }
    #pragma unroll
    for (int j = 0; j < 8; ++j) {
        const int idx = t + NTHREADS * j;
        const int f4 = idx & 15, r = idx >> 4;
        const int pos = (((f4 >> 1) ^ (r & 7)) << 3) + ((f4 & 1) << 2);
        *(u32x2*)&sB[0][r * NF + pos] = pack4(tB[j]);
    }
    if (EPB > 1) {
        #pragma unroll
        for (int j = 0; j < 8; ++j) {
            const int idx = t + NTHREADS * j;
            const int f4 = idx & 15, l = idx >> 4;
            tA[j] = *(const f32x4*)(lig_feat + (((long)b * NL + l) * NE + e0 + 1) * NF + f4 * 4);
        }
        #pragma unroll
        for (int j = 0; j < 8; ++j) {
            const int idx = t + NTHREADS * j;
            const int f4 = idx & 15, r = idx >> 4;
            tB[j] = *(const f32x4*)(rec_feat + (((long)b * NR + r0 + r) * NE + e0 + 1) * NF + f4 * 4);
        }
    }
    __syncthreads();   // buf0 visible

    const float inv_s   = 32.0f / 12.0f;       // |1/sigma|
    const int sw = (n & 7);
    const int aRow0 = (wl * 64 + n) * NF;      // sub-tile i2=1 at +32*NF
    const int bRow0 = (wr * 64 + n) * NF;

    float sum = 0.0f;

    for (int ep = 0; ep < EPB; ++ep) {
        const int cur = ep & 1;

        // -- write regs (e_{ep+1}) to other buffer; reload regs with e_{ep+2} --
        if (ep + 1 < EPB) {
            #pragma unroll
            for (int j = 0; j < 8; ++j) {
                const int idx = t + NTHREADS * j;
                const int f4 = idx & 15, l = idx >> 4;
                const int pos = (((f4 >> 1) ^ (l & 7)) << 3) + ((f4 & 1) << 2);
                *(u32x2*)&sA[cur ^ 1][l * NF + pos] = pack4(tA[j]);
            }
            #pragma unroll
            for (int j = 0; j < 8; ++j) {
                const int idx = t + NTHREADS * j;
                const int f4 = idx & 15, r = idx >> 4;
                const int pos = (((f4 >> 1) ^ (r & 7)) << 3) + ((f4 & 1) << 2);
                *(u32x2*)&sB[cur ^ 1][r * NF + pos] = pack4(tB[j]);
            }
        }
        if (ep + 2 < EPB) {
            const int en = e0 + ep + 2;
            #pragma unroll
            for (int j = 0; j < 8; ++j) {
                const int idx = t + NTHREADS * j;
                const int f4 = idx & 15, l = idx >> 4;
                tA[j] = *(const f32x4*)(lig_feat + (((long)b * NL + l) * NE + en) * NF + f4 * 4);
            }
            #pragma unroll
            for (int j = 0; j < 8; ++j) {
                const int idx = t + NTHREADS * j;
                const int f4 = idx & 15, r = idx >> 4;
                tB[j] = *(const f32x4*)(rec_feat + (((long)b * NR + r0 + r) * NE + en) * NF + f4 * 4);
            }
        }

        // -- compute: 2x2 sub-tiles, fragments register-reused --
        f32x16 acc00 = {0,0,0,0,0,0,0,0,0,0,0,0,0,0,0,0};
        f32x16 acc01 = acc00, acc10 = acc00, acc11 = acc00;
        #pragma unroll
        for (int kc = 0; kc < 4; ++kc) {
            const int off = (((kc * 2 + h) ^ sw) << 3);
            const s16x8 a0 = *(const s16x8*)&sA[cur][aRow0 + off];
            const s16x8 a1 = *(const s16x8*)&sA[cur][aRow0 + 32 * NF + off];
            const s16x8 b0 = *(const s16x8*)&sB[cur][bRow0 + off];
            const s16x8 b1 = *(const s16x8*)&sB[cur][bRow0 + 32 * NF + off];
            acc00 = __builtin_amdgcn_mfma_f32_32x32x16_bf16(a0, b0, acc00, 0, 0, 0);
            acc01 = __builtin_amdgcn_mfma_f32_32x32x16_bf16(a0, b1, acc01, 0, 0, 0);
            acc10 = __builtin_amdgcn_mfma_f32_32x32x16_bf16(a1, b0, acc10, 0, 0, 0);
            acc11 = __builtin_amdgcn_mfma_f32_32x32x16_bf16(a1, b1, acc11, 0, 0, 0);
        }
        // z = d*c - mu*c ; mu_e*c = e * (12/31) * (32/12) = e * 32/31
        const float nmu = -(float)(e0 + ep) * (32.0f / 31.0f);
        #pragma unroll
        for (int i = 0; i < 16; ++i) {
            float z;
            z = __builtin_fmaf(d[0][0][i], inv_s, nmu); sum += __expf(-z * z) * acc00[i];
            z = __builtin_fmaf(d[0][1][i], inv_s, nmu); sum += __expf(-z * z) * acc01[i];
            z = __builtin_fmaf(d[1][0][i], inv_s, nmu); sum += __expf(-z * z) * acc10[i];
            z = __builtin_fmaf(d[1][1][i], inv_s, nmu); sum += __expf(-z * z) * acc11[i];
        }

        if (ep + 1 < EPB) __syncthreads();
    }

    // ---- reduce: wave -> block -> global atomic ----
    sum *= 0.01f;   // ENERGY_SCALE
    #pragma unroll
    for (int off = 32; off > 0; off >>= 1)
        sum += __shfl_down(sum, off, 64);
    if (lane == 0) sRed[wv] = sum;
    __syncthreads();
    if (t == 0) {
        float s = 0.f;
        #pragma unroll
        for (int w = 0; w < NWAVES; ++w) s += sRed[w];
        atomicAdd(&out[b], s);
    }
}

extern "C" void kernel_launch(void* const* d_in, const int* in_sizes, int n_in,
                              void* d_out, int out_size, void* d_ws, size_t ws_size,
                              hipStream_t stream) {
    const float* lig_feat  = (const float*)d_in[0];
    const float* rec_feat  = (const float*)d_in[1];
    const float* lig_coord = (const float*)d_in[2];
    const float* rec_coord = (const float*)d_in[3];
    float* out = (float*)d_out;

    hipMemsetAsync(out, 0, (size_t)out_size * sizeof(float), stream);

    dim3 grid(NB * NRT * EH);   // 512 blocks: (b, r-tile, e-group)
    ff_kernel<<<grid, NTHREADS, 0, stream>>>(lig_feat, rec_feat,
                                             lig_coord, rec_coord, out);
}